// Round 3
// baseline (1292.700 us; speedup 1.0000x reference)
//
#include <hip/hip_runtime.h>

namespace {
constexpr float kL2Reg  = 0.1f;
constexpr float kRho    = 1.0f;   // == 1: s = z - u, no multiply needed
constexpr float kSigma  = 2.0f * kL2Reg + kRho;   // 1.2
constexpr float kJitter = 1e-5f;
constexpr int   kIters  = 100;
constexpr int   MD = 16;     // constraint rows
constexpr int   ND = 32;     // variables
constexpr int   SPB = 8;     // samples per 256-thread block (2 per wave, 32 lanes each)
constexpr int   AS  = 132;   // A sample stride in float4 (528 floats; 528%32==16)
constexpr int   SS  = 36;    // s-slot stride in floats (36%32==4)
}

// A tile in LDS: per sample 16 rows x 8 float4, f4 index xor-swizzled with row.
// Row f4-reads: <=2-way. Column scalar reads A[k][l]: bank = perm(l) -> conflict-free.
__device__ __forceinline__ float4 lds_a4(const float* As, int r, int j) {
    return *reinterpret_cast<const float4*>(&As[r * 32 + ((j ^ (r & 7)) << 2)]);
}
__device__ __forceinline__ float lds_a(const float* As, int r, int n) {
    return As[r * 32 + ((((n >> 2) ^ (r & 7)) << 2) | (n & 3))];
}

__global__ void __launch_bounds__(256, 4)
admm_qp_kernel(const float* __restrict__ Ag, const float* __restrict__ bg,
               const float* __restrict__ cg, const float* __restrict__ lbg,
               const float* __restrict__ ubg, float* __restrict__ outg)
{
    __shared__ __align__(16) float A_lds[SPB * AS * 4];   // 16896 B
    __shared__ __align__(16) float S_lds[SPB * SS];       //  1152 B

    const int t = threadIdx.x;

    // ---- stage A for the block's 8 samples (coalesced, xor-swizzled f4)
    {
        const float4* src = reinterpret_cast<const float4*>(Ag) +
                            (size_t)blockIdx.x * (SPB * MD * ND / 4);
        float4* dst = reinterpret_cast<float4*>(A_lds);
        #pragma unroll
        for (int r = 0; r < 4; ++r) {               // 1024 f4 / 256 threads
            int idx = r * 256 + t;
            int smp = idx >> 7;                     // 128 f4 per sample
            int row = (idx >> 3) & 15;
            int j   = idx & 7;
            dst[smp * AS + row * 8 + (j ^ (row & 7))] = src[idx];
        }
    }
    __syncthreads();

    const int lane = t & 63;
    const int l    = lane & 31;                     // variable index (one per lane)
    const int lr   = l & 15;                        // M-row this lane holds (dup in upper 16)
    const int smp  = (t >> 6) * 2 + (lane >> 5);    // sample within block
    const size_t gs = (size_t)blockIdx.x * SPB + smp;
    const float* As = &A_lds[smp * AS * 4];
    float* Sb = &S_lds[smp * SS];

    // ---- M = A A^T + jitter*I, row lr (duplicated across half-groups). Ar dies after.
    float Mrow[16], Vrow[16];
    {
        float Ar[32];
        #pragma unroll
        for (int j = 0; j < 8; ++j) {
            float4 v = lds_a4(As, lr, j);
            Ar[4*j+0] = v.x; Ar[4*j+1] = v.y; Ar[4*j+2] = v.z; Ar[4*j+3] = v.w;
        }
        #pragma unroll
        for (int k = 0; k < 16; ++k) {
            float a0 = 0.f, a1 = 0.f, a2 = 0.f, a3 = 0.f;
            #pragma unroll
            for (int j = 0; j < 8; ++j) {
                float4 v = lds_a4(As, k, j);
                a0 += Ar[4*j+0]*v.x; a1 += Ar[4*j+1]*v.y;
                a2 += Ar[4*j+2]*v.z; a3 += Ar[4*j+3]*v.w;
            }
            Mrow[k] = (a0+a1)+(a2+a3) + ((k == lr) ? kJitter : 0.f);
            Vrow[k] = (k == lr) ? 1.f : 0.f;
        }
    }

    // ---- Gauss-Jordan inverse (SPD, no pivoting). Width-32 shuffles; pivot rows 0..15.
    #pragma unroll
    for (int k = 0; k < 16; ++k) {
        float ip = 1.f / __shfl(Mrow[k], k, 32);
        float f  = (lr == k) ? 0.f : Mrow[k] * ip;
        #pragma unroll
        for (int j = k; j < 16; ++j) {
            float mj = __shfl(Mrow[j], k, 32);
            Mrow[j] = (lr == k) ? mj * ip : Mrow[j] - f * mj;
        }
        #pragma unroll
        for (int j = 0; j < 16; ++j) {
            float vj = __shfl(Vrow[j], k, 32);
            Vrow[j] = (lr == k) ? vj * ip : Vrow[j] - f * vj;
        }
    }

    // ---- w = Minv b (lane holds w[lr], duplicated)
    float w;
    {
        float bval = bg[gs * MD + lr];
        float acc = 0.f;
        #pragma unroll
        for (int k = 0; k < 16; ++k) acc += Vrow[k] * __shfl(bval, k, 32);
        w = acc;
    }

    // ---- C[m] = sum_k A[k][l] * Minv[k][m]   (row l of C = A^T Minv). Vrow dies after.
    float C[16];
    #pragma unroll
    for (int m = 0; m < 16; ++m) C[m] = 0.f;
    #pragma unroll
    for (int k = 0; k < 16; ++k) {
        float a = lds_a(As, k, l);
        #pragma unroll
        for (int m = 0; m < 16; ++m) C[m] += a * __shfl(Vrow[m], k, 32);
    }

    // ---- P row l = (I - C A)/sigma, packed pairs Pv[j] = (P[l][2j], P[l][2j+1]).
    float2 Pv[16];
    #pragma unroll
    for (int j2 = 0; j2 < 16; ++j2) Pv[j2] = make_float2(0.f, 0.f);
    #pragma unroll
    for (int m = 0; m < 16; ++m) {
        float cm = C[m];
        #pragma unroll
        for (int j = 0; j < 8; ++j) {
            float4 v = lds_a4(As, m, j);
            Pv[2*j+0].x += cm * v.x; Pv[2*j+0].y += cm * v.y;
            Pv[2*j+1].x += cm * v.z; Pv[2*j+1].y += cm * v.w;
        }
    }
    constexpr float is = 1.f / kSigma;
    #pragma unroll
    for (int j2 = 0; j2 < 16; ++j2) {
        Pv[j2].x = (((2*j2 + 0) == l ? 1.f : 0.f) - Pv[j2].x) * is;
        Pv[j2].y = (((2*j2 + 1) == l ? 1.f : 0.f) - Pv[j2].y) * is;
    }

    // ---- d = A^T w - P c
    float d;
    {
        float q = 0.f;
        #pragma unroll
        for (int m = 0; m < 16; ++m) q += lds_a(As, m, l) * __shfl(w, m, 32);
        float cval = cg[gs * ND + l];
        float pc = 0.f;
        #pragma unroll
        for (int j2 = 0; j2 < 16; ++j2) {
            pc += Pv[j2].x * __shfl(cval, 2*j2 + 0, 32);
            pc += Pv[j2].y * __shfl(cval, 2*j2 + 1, 32);
        }
        d = q - pc;
    }

    // ---- ADMM iterations. One variable per lane; s broadcast via tiny LDS slot.
    float lb = lbg[gs * ND + l];
    float ub = ubg[gs * ND + l];
    float z  = fminf(fmaxf(0.f, lb), ub);
    float u  = 0.f, x = 0.f;

    for (int it = 0; it < kIters; ++it) {
        Sb[l] = z - u;                                   // kRho == 1
        asm volatile("s_waitcnt lgkmcnt(0)" ::: "memory"); // wave-synchronous exchange
        float2 a0 = make_float2(d, 0.f);
        float2 a1 = make_float2(0.f, 0.f);
        float2 a2 = make_float2(0.f, 0.f);
        float2 a3 = make_float2(0.f, 0.f);
        #pragma unroll
        for (int k = 0; k < 4; ++k) {                    // uniform b128 reads (broadcast)
            float4 s0 = *reinterpret_cast<const float4*>(&Sb[k * 8]);
            float4 s1 = *reinterpret_cast<const float4*>(&Sb[k * 8 + 4]);
            a0.x += Pv[4*k+0].x * s0.x;  a0.y += Pv[4*k+0].y * s0.y;
            a1.x += Pv[4*k+1].x * s0.z;  a1.y += Pv[4*k+1].y * s0.w;
            a2.x += Pv[4*k+2].x * s1.x;  a2.y += Pv[4*k+2].y * s1.y;
            a3.x += Pv[4*k+3].x * s1.z;  a3.y += Pv[4*k+3].y * s1.w;
        }
        x = ((a0.x + a0.y) + (a1.x + a1.y)) + ((a2.x + a2.y) + (a3.x + a3.y));
        float tv = x + u;
        z = fminf(fmaxf(tv, lb), ub);
        u = tv - z;
    }

    outg[gs * ND + l] = x;
}

extern "C" void kernel_launch(void* const* d_in, const int* in_sizes, int n_in,
                              void* d_out, int out_size, void* d_ws, size_t ws_size,
                              hipStream_t stream) {
    const float* A  = (const float*)d_in[0];
    const float* b  = (const float*)d_in[1];
    const float* c  = (const float*)d_in[2];
    const float* lb = (const float*)d_in[3];
    const float* ub = (const float*)d_in[4];
    float* out = (float*)d_out;
    const int B = in_sizes[1] / MD;      // 32768 samples
    const int grid = B / SPB;            // 4096 blocks of 256 threads (8 samples each)
    admm_qp_kernel<<<grid, 256, 0, stream>>>(A, b, c, lb, ub, out);
}

// Round 4
// 1291.240 us; speedup vs baseline: 1.0011x; 1.0011x over previous
//
#include <hip/hip_runtime.h>

namespace {
constexpr float kL2Reg  = 0.1f;
constexpr float kRho    = 1.0f;   // == 1: s = z - u, no multiply needed
constexpr float kSigma  = 2.0f * kL2Reg + kRho;   // 1.2
constexpr float kJitter = 1e-5f;
constexpr int   kIters  = 100;
constexpr int   MD = 16;     // constraint rows
constexpr int   ND = 32;     // variables
constexpr int   SPB = 8;     // samples per 256-thread block (2 per wave, 32 lanes each)
constexpr int   AS  = 132;   // A sample stride in float4 (528 floats; 528%32==16)
constexpr int   SS  = 36;    // s-slot stride in floats (36%32==4)
}

// A tile in LDS: per sample 16 rows x 8 float4, f4 index xor-swizzled with row.
__device__ __forceinline__ float4 lds_a4(const float* As, int r, int j) {
    return *reinterpret_cast<const float4*>(&As[r * 32 + ((j ^ (r & 7)) << 2)]);
}
__device__ __forceinline__ float lds_a(const float* As, int r, int n) {
    return As[r * 32 + ((((n >> 2) ^ (r & 7)) << 2) | (n & 3))];
}

__global__ void __launch_bounds__(256, 4)
admm_qp_kernel(const float* __restrict__ Ag, const float* __restrict__ bg,
               const float* __restrict__ cg, const float* __restrict__ lbg,
               const float* __restrict__ ubg, float* __restrict__ outg)
{
    __shared__ __align__(16) float A_lds[SPB * AS * 4];   // 16896 B
    __shared__ __align__(16) float S_lds[SPB * SS];       //  1152 B

    const int t = threadIdx.x;

    // ---- stage A for the block's 8 samples (coalesced, xor-swizzled f4)
    {
        const float4* src = reinterpret_cast<const float4*>(Ag) +
                            (size_t)blockIdx.x * (SPB * MD * ND / 4);
        float4* dst = reinterpret_cast<float4*>(A_lds);
        #pragma unroll
        for (int r = 0; r < 4; ++r) {               // 1024 f4 / 256 threads
            int idx = r * 256 + t;
            int smp = idx >> 7;                     // 128 f4 per sample
            int row = (idx >> 3) & 15;
            int j   = idx & 7;
            dst[smp * AS + row * 8 + (j ^ (row & 7))] = src[idx];
        }
    }
    __syncthreads();

    const int lane = t & 63;
    const int l    = lane & 31;                     // variable index (one per lane)
    const int lr   = l & 15;                        // M-row this lane holds (dup in upper 16)
    const int smp  = (t >> 6) * 2 + (lane >> 5);    // sample within block
    const size_t gs = (size_t)blockIdx.x * SPB + smp;
    const float* As = &A_lds[smp * AS * 4];
    float* Sb = &S_lds[smp * SS];

    // ---- M = A A^T + jitter*I, row lr (duplicated across half-groups). Ar dies after.
    float Mrow[16], Vrow[16];
    {
        float Ar[32];
        #pragma unroll
        for (int j = 0; j < 8; ++j) {
            float4 v = lds_a4(As, lr, j);
            Ar[4*j+0] = v.x; Ar[4*j+1] = v.y; Ar[4*j+2] = v.z; Ar[4*j+3] = v.w;
        }
        #pragma unroll
        for (int k = 0; k < 16; ++k) {
            float a0 = 0.f, a1 = 0.f, a2 = 0.f, a3 = 0.f;
            #pragma unroll
            for (int j = 0; j < 8; ++j) {
                float4 v = lds_a4(As, k, j);
                a0 += Ar[4*j+0]*v.x; a1 += Ar[4*j+1]*v.y;
                a2 += Ar[4*j+2]*v.z; a3 += Ar[4*j+3]*v.w;
            }
            Mrow[k] = (a0+a1)+(a2+a3) + ((k == lr) ? kJitter : 0.f);
            Vrow[k] = (k == lr) ? 1.f : 0.f;
        }
    }

    // ---- Gauss-Jordan inverse (SPD, no pivoting). Width-32 shuffles.
    // NOTE: inner loops run the FULL constant range 0..15 (rule #20: a lower
    // bound of `k` defeats inner-loop unrolling -> Mrow/Vrow demoted to scratch,
    // which was R1-R3's 1.6GB/2.6GB FETCH/WRITE). Updates for j<k are no-ops
    // (pivot row is zero there), so full range is mathematically identical.
    #pragma unroll
    for (int k = 0; k < 16; ++k) {
        float ip = 1.f / __shfl(Mrow[k], k, 32);
        float f  = (lr == k) ? 0.f : Mrow[k] * ip;
        #pragma unroll
        for (int j = 0; j < 16; ++j) {
            float mj = __shfl(Mrow[j], k, 32);
            Mrow[j] = (lr == k) ? mj * ip : Mrow[j] - f * mj;
        }
        #pragma unroll
        for (int j = 0; j < 16; ++j) {
            float vj = __shfl(Vrow[j], k, 32);
            Vrow[j] = (lr == k) ? vj * ip : Vrow[j] - f * vj;
        }
    }

    // ---- w = Minv b (lane holds w[lr], duplicated)
    float w;
    {
        float bval = bg[gs * MD + lr];
        float acc = 0.f;
        #pragma unroll
        for (int k = 0; k < 16; ++k) acc += Vrow[k] * __shfl(bval, k, 32);
        w = acc;
    }

    // ---- C[m] = sum_k A[k][l] * Minv[k][m]   (row l of C = A^T Minv). Vrow dies after.
    float C[16];
    #pragma unroll
    for (int m = 0; m < 16; ++m) C[m] = 0.f;
    #pragma unroll
    for (int k = 0; k < 16; ++k) {
        float a = lds_a(As, k, l);
        #pragma unroll
        for (int m = 0; m < 16; ++m) C[m] += a * __shfl(Vrow[m], k, 32);
    }

    // ---- P row l = (I - C A)/sigma, packed pairs Pv[j] = (P[l][2j], P[l][2j+1]).
    float2 Pv[16];
    #pragma unroll
    for (int j2 = 0; j2 < 16; ++j2) Pv[j2] = make_float2(0.f, 0.f);
    #pragma unroll
    for (int m = 0; m < 16; ++m) {
        float cm = C[m];
        #pragma unroll
        for (int j = 0; j < 8; ++j) {
            float4 v = lds_a4(As, m, j);
            Pv[2*j+0].x += cm * v.x; Pv[2*j+0].y += cm * v.y;
            Pv[2*j+1].x += cm * v.z; Pv[2*j+1].y += cm * v.w;
        }
    }
    constexpr float is = 1.f / kSigma;
    #pragma unroll
    for (int j2 = 0; j2 < 16; ++j2) {
        Pv[j2].x = (((2*j2 + 0) == l ? 1.f : 0.f) - Pv[j2].x) * is;
        Pv[j2].y = (((2*j2 + 1) == l ? 1.f : 0.f) - Pv[j2].y) * is;
    }

    // ---- d = A^T w - P c
    float d;
    {
        float q = 0.f;
        #pragma unroll
        for (int m = 0; m < 16; ++m) q += lds_a(As, m, l) * __shfl(w, m, 32);
        float cval = cg[gs * ND + l];
        float pc = 0.f;
        #pragma unroll
        for (int j2 = 0; j2 < 16; ++j2) {
            pc += Pv[j2].x * __shfl(cval, 2*j2 + 0, 32);
            pc += Pv[j2].y * __shfl(cval, 2*j2 + 1, 32);
        }
        d = q - pc;
    }

    // ---- ADMM iterations. One variable per lane; s broadcast via tiny LDS slot.
    float lb = lbg[gs * ND + l];
    float ub = ubg[gs * ND + l];
    float z  = fminf(fmaxf(0.f, lb), ub);
    float u  = 0.f, x = 0.f;

    for (int it = 0; it < kIters; ++it) {
        Sb[l] = z - u;                                   // kRho == 1
        asm volatile("s_waitcnt lgkmcnt(0)" ::: "memory"); // wave-synchronous exchange
        float2 a0 = make_float2(d, 0.f);
        float2 a1 = make_float2(0.f, 0.f);
        float2 a2 = make_float2(0.f, 0.f);
        float2 a3 = make_float2(0.f, 0.f);
        #pragma unroll
        for (int k = 0; k < 4; ++k) {                    // uniform b128 reads (broadcast)
            float4 s0 = *reinterpret_cast<const float4*>(&Sb[k * 8]);
            float4 s1 = *reinterpret_cast<const float4*>(&Sb[k * 8 + 4]);
            a0.x += Pv[4*k+0].x * s0.x;  a0.y += Pv[4*k+0].y * s0.y;
            a1.x += Pv[4*k+1].x * s0.z;  a1.y += Pv[4*k+1].y * s0.w;
            a2.x += Pv[4*k+2].x * s1.x;  a2.y += Pv[4*k+2].y * s1.y;
            a3.x += Pv[4*k+3].x * s1.z;  a3.y += Pv[4*k+3].y * s1.w;
        }
        x = ((a0.x + a0.y) + (a1.x + a1.y)) + ((a2.x + a2.y) + (a3.x + a3.y));
        float tv = x + u;
        z = fminf(fmaxf(tv, lb), ub);
        u = tv - z;
    }

    outg[gs * ND + l] = x;
}

extern "C" void kernel_launch(void* const* d_in, const int* in_sizes, int n_in,
                              void* d_out, int out_size, void* d_ws, size_t ws_size,
                              hipStream_t stream) {
    const float* A  = (const float*)d_in[0];
    const float* b  = (const float*)d_in[1];
    const float* c  = (const float*)d_in[2];
    const float* lb = (const float*)d_in[3];
    const float* ub = (const float*)d_in[4];
    float* out = (float*)d_out;
    const int B = in_sizes[1] / MD;      // 32768 samples
    const int grid = B / SPB;            // 4096 blocks of 256 threads (8 samples each)
    admm_qp_kernel<<<grid, 256, 0, stream>>>(A, b, c, lb, ub, out);
}

// Round 5
// 1187.932 us; speedup vs baseline: 1.0882x; 1.0870x over previous
//
#include <hip/hip_runtime.h>

typedef float f16v __attribute__((ext_vector_type(16)));

namespace {
constexpr float kSigma  = 1.2f;    // 2*l2_reg + rho
constexpr float kJitter = 1e-5f;
constexpr int   kIters  = 100;
constexpr int   MD = 16;     // constraint rows
constexpr int   ND = 32;     // variables
constexpr int   SPB = 8;     // samples per 256-thread block (2 per wave, 32 lanes each)
constexpr int   AS  = 132;   // A sample stride in float4 (528 floats; 528%32==16)
constexpr int   SS  = 36;    // s-slot stride in floats (36%32==4)
}

// A tile in LDS: per sample 16 rows x 8 float4, f4 index xor-swizzled with row.
__device__ __forceinline__ float4 lds_a4(const float* As, int r, int j) {
    return *reinterpret_cast<const float4*>(&As[r * 32 + ((j ^ (r & 7)) << 2)]);
}
__device__ __forceinline__ float lds_a(const float* As, int r, int n) {
    return As[r * 32 + ((((n >> 2) ^ (r & 7)) << 2) | (n & 3))];
}

__global__ void __launch_bounds__(256, 4)
admm_qp_kernel(const float* __restrict__ Ag, const float* __restrict__ bg,
               const float* __restrict__ cg, const float* __restrict__ lbg,
               const float* __restrict__ ubg, float* __restrict__ outg)
{
    __shared__ __align__(16) float A_lds[SPB * AS * 4];   // 16896 B
    __shared__ __align__(16) float S_lds[SPB * SS];       //  1152 B

    const int t = threadIdx.x;

    // ---- stage A for the block's 8 samples (coalesced, xor-swizzled f4)
    {
        const float4* src = reinterpret_cast<const float4*>(Ag) +
                            (size_t)blockIdx.x * (SPB * MD * ND / 4);
        float4* dst = reinterpret_cast<float4*>(A_lds);
        #pragma unroll
        for (int r = 0; r < 4; ++r) {               // 1024 f4 / 256 threads
            int idx = r * 256 + t;
            int smp = idx >> 7;                     // 128 f4 per sample
            int row = (idx >> 3) & 15;
            int j   = idx & 7;
            dst[smp * AS + row * 8 + (j ^ (row & 7))] = src[idx];
        }
    }
    __syncthreads();

    const int lane = t & 63;
    const int l    = lane & 31;                     // variable index (one per lane)
    const int lr   = l & 15;                        // M-row this lane holds (dup upper 16)
    const int smp  = (t >> 6) * 2 + (lane >> 5);    // sample within block
    const size_t gs = (size_t)blockIdx.x * SPB + smp;
    const float* As = &A_lds[smp * AS * 4];
    float* Sb = &S_lds[smp * SS];

    // ---- M = A A^T + jitter*I (row lr) into a vector (SSA, never scratch)
    f16v Mrow, Vrow;
    {
        f16v Ar0, Ar1;                              // own A row; dies after this block
        #pragma unroll
        for (int j = 0; j < 4; ++j) {
            float4 v = lds_a4(As, lr, j);
            Ar0[4*j+0] = v.x; Ar0[4*j+1] = v.y; Ar0[4*j+2] = v.z; Ar0[4*j+3] = v.w;
            float4 w4 = lds_a4(As, lr, j + 4);
            Ar1[4*j+0] = w4.x; Ar1[4*j+1] = w4.y; Ar1[4*j+2] = w4.z; Ar1[4*j+3] = w4.w;
        }
        #pragma unroll
        for (int k = 0; k < 16; ++k) {
            float a0 = 0.f, a1 = 0.f, a2 = 0.f, a3 = 0.f;
            #pragma unroll
            for (int j = 0; j < 4; ++j) {
                float4 v  = lds_a4(As, k, j);
                a0 += Ar0[4*j+0]*v.x;  a1 += Ar0[4*j+1]*v.y;
                a2 += Ar0[4*j+2]*v.z;  a3 += Ar0[4*j+3]*v.w;
                float4 w4 = lds_a4(As, k, j + 4);
                a0 += Ar1[4*j+0]*w4.x; a1 += Ar1[4*j+1]*w4.y;
                a2 += Ar1[4*j+2]*w4.z; a3 += Ar1[4*j+3]*w4.w;
            }
            Mrow[k] = (a0+a1)+(a2+a3) + ((k == lr) ? kJitter : 0.f);
            Vrow[k] = (k == lr) ? 1.f : 0.f;
        }
    }

    // ---- Gauss-Jordan inverse (SPD -> no pivoting), width-32 shuffles
    #pragma unroll
    for (int k = 0; k < 16; ++k) {
        float ip = 1.f / __shfl(Mrow[k], k, 32);
        float f  = (lr == k) ? 0.f : Mrow[k] * ip;
        #pragma unroll
        for (int j = 0; j < 16; ++j) {
            float mj = __shfl(Mrow[j], k, 32);
            Mrow[j] = (lr == k) ? mj * ip : Mrow[j] - f * mj;
            float vj = __shfl(Vrow[j], k, 32);
            Vrow[j] = (lr == k) ? vj * ip : Vrow[j] - f * vj;
        }
    }

    // ---- w = Minv b (lane holds w[lr], duplicated across half-groups)
    float w = 0.f;
    {
        float bval = bg[gs * MD + lr];
        #pragma unroll
        for (int k = 0; k < 16; ++k) w += Vrow[k] * __shfl(bval, k, 32);
    }

    // ---- C row l of A^T Minv. Vrow dies after this.
    f16v C = (f16v)0.0f;
    #pragma unroll
    for (int k = 0; k < 16; ++k) {
        float a = lds_a(As, k, l);
        #pragma unroll
        for (int m = 0; m < 16; ++m) C[m] += a * __shfl(Vrow[m], k, 32);
    }

    // ---- P row l = (I - C A)/sigma: Pa[n]=P[l][n], Pb[n]=P[l][n+16]
    f16v Pa = (f16v)0.0f, Pb = (f16v)0.0f;
    #pragma unroll
    for (int m = 0; m < 16; ++m) {
        float cm = C[m];
        #pragma unroll
        for (int j = 0; j < 4; ++j) {
            float4 v  = lds_a4(As, m, j);
            Pa[4*j+0] += cm*v.x;  Pa[4*j+1] += cm*v.y;
            Pa[4*j+2] += cm*v.z;  Pa[4*j+3] += cm*v.w;
            float4 w4 = lds_a4(As, m, j + 4);
            Pb[4*j+0] += cm*w4.x; Pb[4*j+1] += cm*w4.y;
            Pb[4*j+2] += cm*w4.z; Pb[4*j+3] += cm*w4.w;
        }
    }
    constexpr float is = 1.f / kSigma;
    #pragma unroll
    for (int n = 0; n < 16; ++n) {
        Pa[n] = (((n      == l) ? 1.f : 0.f) - Pa[n]) * is;
        Pb[n] = (((n + 16 == l) ? 1.f : 0.f) - Pb[n]) * is;
    }

    // ---- d = A^T w - P c
    float d;
    {
        float q = 0.f;
        #pragma unroll
        for (int m = 0; m < 16; ++m) q += lds_a(As, m, l) * __shfl(w, m, 32);
        float cval = cg[gs * ND + l];
        float pc0 = 0.f, pc1 = 0.f;
        #pragma unroll
        for (int n = 0; n < 16; ++n) {
            pc0 += Pa[n] * __shfl(cval, n,      32);
            pc1 += Pb[n] * __shfl(cval, n + 16, 32);
        }
        d = q - (pc0 + pc1);
    }

    // ---- ADMM iterations. One variable per lane; s broadcast via tiny LDS slot.
    float lb = lbg[gs * ND + l];
    float ub = ubg[gs * ND + l];
    float z  = fminf(fmaxf(0.f, lb), ub);
    float u  = 0.f, x = 0.f;

    for (int it = 0; it < kIters; ++it) {
        Sb[l] = z - u;                                     // rho == 1
        asm volatile("s_waitcnt lgkmcnt(0)" ::: "memory"); // wave-synchronous exchange
        float a0 = d, a1 = 0.f, a2 = 0.f, a3 = 0.f;
        #pragma unroll
        for (int k = 0; k < 4; ++k) {                      // uniform b128 reads (broadcast)
            float4 sA = *reinterpret_cast<const float4*>(&Sb[4*k]);
            float4 sB = *reinterpret_cast<const float4*>(&Sb[4*k + 16]);
            a0 += Pa[4*k+0]*sA.x + Pb[4*k+0]*sB.x;
            a1 += Pa[4*k+1]*sA.y + Pb[4*k+1]*sB.y;
            a2 += Pa[4*k+2]*sA.z + Pb[4*k+2]*sB.z;
            a3 += Pa[4*k+3]*sA.w + Pb[4*k+3]*sB.w;
        }
        x = (a0 + a1) + (a2 + a3);
        float tv = x + u;
        z = fminf(fmaxf(tv, lb), ub);
        u = tv - z;
    }

    outg[gs * ND + l] = x;
}

extern "C" void kernel_launch(void* const* d_in, const int* in_sizes, int n_in,
                              void* d_out, int out_size, void* d_ws, size_t ws_size,
                              hipStream_t stream) {
    const float* A  = (const float*)d_in[0];
    const float* b  = (const float*)d_in[1];
    const float* c  = (const float*)d_in[2];
    const float* lb = (const float*)d_in[3];
    const float* ub = (const float*)d_in[4];
    float* out = (float*)d_out;
    const int B = in_sizes[1] / MD;      // 32768 samples
    const int grid = B / SPB;            // 4096 blocks of 256 threads (8 samples each)
    admm_qp_kernel<<<grid, 256, 0, stream>>>(A, b, c, lb, ub, out);
}

// Round 6
// 804.296 us; speedup vs baseline: 1.6072x; 1.4770x over previous
//
#include <hip/hip_runtime.h>

typedef float f16v __attribute__((ext_vector_type(16)));

// static_for: indices are compile-time constants AT THE FRONTEND, so vector
// subscripts lower to constant-index insert/extractelement (pure SSA, no
// alloca). #pragma unroll loop vars are NOT frontend-constant -> clang emits
// variable-GEP stores into the vector's alloca -> SROA fails -> scratch.
// That alloca was R1-R5's 1.3-2.6 GB of FETCH/WRITE scratch traffic.
template<int I> struct ic { static constexpr int v = I; };
template<int... I> struct iseq {};
template<int N, int... I> struct mk : mk<N-1, N-1, I...> {};
template<int... I> struct mk<0, I...> { using t = iseq<I...>; };
template<class F, int... I>
__device__ __forceinline__ void sfor_impl(F f, iseq<I...>) { (f(ic<I>{}), ...); }
template<int N, class F>
__device__ __forceinline__ void sfor(F f) { sfor_impl(f, typename mk<N>::t{}); }

namespace {
constexpr float kSigma  = 1.2f;    // 2*l2_reg + rho
constexpr float kJitter = 1e-5f;
constexpr int   kIters  = 100;
constexpr int   MD = 16;     // constraint rows
constexpr int   ND = 32;     // variables
constexpr int   SPB = 8;     // samples per 256-thread block (2 per wave, 32 lanes each)
constexpr int   AS  = 132;   // A sample stride in float4 (528 floats; 528%32==16)
constexpr int   SS  = 36;    // s-slot stride in floats (36%32==4)
}

// A tile in LDS: per sample 16 rows x 8 float4, f4 index xor-swizzled with row.
__device__ __forceinline__ float4 lds_a4(const float* As, int r, int j) {
    return *reinterpret_cast<const float4*>(&As[r * 32 + ((j ^ (r & 7)) << 2)]);
}
__device__ __forceinline__ float lds_a(const float* As, int r, int n) {
    return As[r * 32 + ((((n >> 2) ^ (r & 7)) << 2) | (n & 3))];
}

__global__ void __launch_bounds__(256)
admm_qp_kernel(const float* __restrict__ Ag, const float* __restrict__ bg,
               const float* __restrict__ cg, const float* __restrict__ lbg,
               const float* __restrict__ ubg, float* __restrict__ outg)
{
    __shared__ __align__(16) float A_lds[SPB * AS * 4];   // 16896 B
    __shared__ __align__(16) float S_lds[SPB * SS];       //  1152 B

    const int t = threadIdx.x;

    // ---- stage A for the block's 8 samples (coalesced, xor-swizzled f4)
    {
        const float4* src = reinterpret_cast<const float4*>(Ag) +
                            (size_t)blockIdx.x * (SPB * MD * ND / 4);
        float4* dst = reinterpret_cast<float4*>(A_lds);
        #pragma unroll
        for (int r = 0; r < 4; ++r) {               // 1024 f4 / 256 threads
            int idx = r * 256 + t;
            int smp = idx >> 7;                     // 128 f4 per sample
            int row = (idx >> 3) & 15;
            int j   = idx & 7;
            dst[smp * AS + row * 8 + (j ^ (row & 7))] = src[idx];
        }
    }
    __syncthreads();

    const int lane = t & 63;
    const int l    = lane & 31;                     // variable index (one per lane)
    const int lr   = l & 15;                        // M-row this lane holds (dup upper 16)
    const int smp  = (t >> 6) * 2 + (lane >> 5);    // sample within block
    const size_t gs = (size_t)blockIdx.x * SPB + smp;
    const float* As = &A_lds[smp * AS * 4];
    float* Sb = &S_lds[smp * SS];

    // ---- M = A A^T + jitter*I (row lr)
    f16v Mrow, Vrow;
    {
        f16v Ar0, Ar1;                              // own A row; dies after this block
        sfor<4>([&](auto J) {
            constexpr int j = decltype(J)::v;
            float4 v  = lds_a4(As, lr, j);
            Ar0[4*j+0] = v.x;  Ar0[4*j+1] = v.y;  Ar0[4*j+2] = v.z;  Ar0[4*j+3] = v.w;
            float4 w4 = lds_a4(As, lr, j + 4);
            Ar1[4*j+0] = w4.x; Ar1[4*j+1] = w4.y; Ar1[4*j+2] = w4.z; Ar1[4*j+3] = w4.w;
        });
        sfor<16>([&](auto K) {
            constexpr int k = decltype(K)::v;
            float a0 = 0.f, a1 = 0.f, a2 = 0.f, a3 = 0.f;
            sfor<4>([&](auto J) {
                constexpr int j = decltype(J)::v;
                float4 v  = lds_a4(As, k, j);
                a0 += Ar0[4*j+0]*v.x;  a1 += Ar0[4*j+1]*v.y;
                a2 += Ar0[4*j+2]*v.z;  a3 += Ar0[4*j+3]*v.w;
                float4 w4 = lds_a4(As, k, j + 4);
                a0 += Ar1[4*j+0]*w4.x; a1 += Ar1[4*j+1]*w4.y;
                a2 += Ar1[4*j+2]*w4.z; a3 += Ar1[4*j+3]*w4.w;
            });
            Mrow[k] = (a0+a1)+(a2+a3) + ((k == lr) ? kJitter : 0.f);
            Vrow[k] = (k == lr) ? 1.f : 0.f;
        });
    }

    // ---- Gauss-Jordan inverse (SPD -> no pivoting), width-32 shuffles
    sfor<16>([&](auto K) {
        constexpr int k = decltype(K)::v;
        float ip = 1.f / __shfl(Mrow[k], k, 32);
        float f  = (lr == k) ? 0.f : Mrow[k] * ip;
        sfor<16>([&](auto J) {
            constexpr int j = decltype(J)::v;
            float mj = __shfl(Mrow[j], k, 32);
            Mrow[j] = (lr == k) ? mj * ip : Mrow[j] - f * mj;
            float vj = __shfl(Vrow[j], k, 32);
            Vrow[j] = (lr == k) ? vj * ip : Vrow[j] - f * vj;
        });
    });

    // ---- w = Minv b (lane holds w[lr], duplicated across half-groups)
    float w = 0.f;
    {
        float bval = bg[gs * MD + lr];
        sfor<16>([&](auto K) {
            constexpr int k = decltype(K)::v;
            w += Vrow[k] * __shfl(bval, k, 32);
        });
    }

    // ---- C row l of A^T Minv. Vrow dies after this.
    f16v C = (f16v)0.0f;
    sfor<16>([&](auto K) {
        constexpr int k = decltype(K)::v;
        float a = lds_a(As, k, l);
        sfor<16>([&](auto M) {
            constexpr int m = decltype(M)::v;
            C[m] += a * __shfl(Vrow[m], k, 32);
        });
    });

    // ---- P row l = (I - C A)/sigma: Pa[n]=P[l][n], Pb[n]=P[l][n+16]
    f16v Pa = (f16v)0.0f, Pb = (f16v)0.0f;
    sfor<16>([&](auto M) {
        constexpr int m = decltype(M)::v;
        float cm = C[m];
        sfor<4>([&](auto J) {
            constexpr int j = decltype(J)::v;
            float4 v  = lds_a4(As, m, j);
            Pa[4*j+0] += cm*v.x;  Pa[4*j+1] += cm*v.y;
            Pa[4*j+2] += cm*v.z;  Pa[4*j+3] += cm*v.w;
            float4 w4 = lds_a4(As, m, j + 4);
            Pb[4*j+0] += cm*w4.x; Pb[4*j+1] += cm*w4.y;
            Pb[4*j+2] += cm*w4.z; Pb[4*j+3] += cm*w4.w;
        });
    });
    constexpr float is = 1.f / kSigma;
    sfor<16>([&](auto N) {
        constexpr int n = decltype(N)::v;
        Pa[n] = (((n      == l) ? 1.f : 0.f) - Pa[n]) * is;
        Pb[n] = (((n + 16 == l) ? 1.f : 0.f) - Pb[n]) * is;
    });

    // ---- d = A^T w - P c
    float d;
    {
        float q = 0.f;
        sfor<16>([&](auto M) {
            constexpr int m = decltype(M)::v;
            q += lds_a(As, m, l) * __shfl(w, m, 32);
        });
        float cval = cg[gs * ND + l];
        float pc0 = 0.f, pc1 = 0.f;
        sfor<16>([&](auto N) {
            constexpr int n = decltype(N)::v;
            pc0 += Pa[n] * __shfl(cval, n,      32);
            pc1 += Pb[n] * __shfl(cval, n + 16, 32);
        });
        d = q - (pc0 + pc1);
    }

    // ---- ADMM iterations. One variable per lane; s broadcast via tiny LDS slot.
    float lb = lbg[gs * ND + l];
    float ub = ubg[gs * ND + l];
    float z  = fminf(fmaxf(0.f, lb), ub);
    float u  = 0.f, x = 0.f;

    for (int it = 0; it < kIters; ++it) {
        Sb[l] = z - u;                                     // rho == 1
        asm volatile("s_waitcnt lgkmcnt(0)" ::: "memory"); // wave-synchronous exchange
        float a0 = d, a1 = 0.f, a2 = 0.f, a3 = 0.f;
        sfor<4>([&](auto K) {                              // uniform b128 reads (broadcast)
            constexpr int k = decltype(K)::v;
            float4 sA = *reinterpret_cast<const float4*>(&Sb[4*k]);
            float4 sB = *reinterpret_cast<const float4*>(&Sb[4*k + 16]);
            a0 += Pa[4*k+0]*sA.x + Pb[4*k+0]*sB.x;
            a1 += Pa[4*k+1]*sA.y + Pb[4*k+1]*sB.y;
            a2 += Pa[4*k+2]*sA.z + Pb[4*k+2]*sB.z;
            a3 += Pa[4*k+3]*sA.w + Pb[4*k+3]*sB.w;
        });
        x = (a0 + a1) + (a2 + a3);
        float tv = x + u;
        z = fminf(fmaxf(tv, lb), ub);
        u = tv - z;
    }

    outg[gs * ND + l] = x;
}

extern "C" void kernel_launch(void* const* d_in, const int* in_sizes, int n_in,
                              void* d_out, int out_size, void* d_ws, size_t ws_size,
                              hipStream_t stream) {
    const float* A  = (const float*)d_in[0];
    const float* b  = (const float*)d_in[1];
    const float* c  = (const float*)d_in[2];
    const float* lb = (const float*)d_in[3];
    const float* ub = (const float*)d_in[4];
    float* out = (float*)d_out;
    const int B = in_sizes[1] / MD;      // 32768 samples
    const int grid = B / SPB;            // 4096 blocks of 256 threads (8 samples each)
    admm_qp_kernel<<<grid, 256, 0, stream>>>(A, b, c, lb, ub, out);
}

// Round 7
// 344.434 us; speedup vs baseline: 3.7531x; 2.3351x over previous
//
#include <hip/hip_runtime.h>

typedef float f16v __attribute__((ext_vector_type(16)));

// static_for with FRONTEND-constant indices: vector subscripts lower to
// constant-index insert/extractelement (SSA, no alloca). #pragma unroll loop
// vars are not frontend-constant -> variable GEP -> alloca -> scratch traffic
// (R1-R5's GBs of FETCH/WRITE; R6 proved this mechanism by fixing FETCH).
template<int I> struct ic { static constexpr int v = I; };
template<int... I> struct iseq {};
template<int N, int... I> struct mk : mk<N-1, N-1, I...> {};
template<int... I> struct mk<0, I...> { using t = iseq<I...>; };
template<class F, int... I>
__device__ __forceinline__ void sfor_impl(F f, iseq<I...>) { (f(ic<I>{}), ...); }
template<int N, class F>
__device__ __forceinline__ void sfor(F f) { sfor_impl(f, typename mk<N>::t{}); }

namespace {
constexpr float kSigma  = 1.2f;    // 2*l2_reg + rho
constexpr float kJitter = 1e-5f;
constexpr int   kIters  = 100;
constexpr int   MD = 16;     // constraint rows
constexpr int   ND = 32;     // variables
constexpr int   SPB = 8;     // samples per 256-thread block (2 per wave, 32 lanes each)
constexpr int   AS  = 132;   // A sample stride in float4 (528 floats; 528%32==16)
constexpr int   SS  = 36;    // s-slot stride in floats
constexpr int   MIS = 20;    // Minv row stride in floats (80B: b128-aligned, 2-way banks)
}

// A tile in LDS: per sample 16 rows x 8 float4, f4 index xor-swizzled with row.
__device__ __forceinline__ float4 lds_a4(const float* As, int r, int j) {
    return *reinterpret_cast<const float4*>(&As[r * 32 + ((j ^ (r & 7)) << 2)]);
}
__device__ __forceinline__ float lds_a(const float* As, int r, int n) {
    return As[r * 32 + ((((n >> 2) ^ (r & 7)) << 2) | (n & 3))];
}

// ============================ Kernel A: precompute P, d ============================
__global__ void __launch_bounds__(256)
precompute_kernel(const float* __restrict__ Ag, const float* __restrict__ bg,
                  const float* __restrict__ cg, float* __restrict__ Pws,
                  float* __restrict__ dws)
{
    __shared__ __align__(16) float A_lds[SPB * AS * 4];       // 16896 B
    __shared__ __align__(16) float Minv_lds[SPB * MD * MIS];  // 10240 B

    const int t = threadIdx.x;

    // ---- stage A for the block's 8 samples (coalesced, xor-swizzled f4)
    {
        const float4* src = reinterpret_cast<const float4*>(Ag) +
                            (size_t)blockIdx.x * (SPB * MD * ND / 4);
        float4* dst = reinterpret_cast<float4*>(A_lds);
        #pragma unroll
        for (int r = 0; r < 4; ++r) {
            int idx = r * 256 + t;
            int smp = idx >> 7;
            int row = (idx >> 3) & 15;
            int j   = idx & 7;
            dst[smp * AS + row * 8 + (j ^ (row & 7))] = src[idx];
        }
    }
    __syncthreads();

    const int lane = t & 63;
    const int l    = lane & 31;
    const int lr   = l & 15;
    const int smp  = (t >> 6) * 2 + (lane >> 5);
    const size_t gs = (size_t)blockIdx.x * SPB + smp;
    const float* As = &A_lds[smp * AS * 4];
    float* Mi = &Minv_lds[smp * MD * MIS];

    // ---- M = A A^T + jitter*I (row lr); both operand rows from LDS (no Ar regs)
    f16v Mrow, Vrow;
    sfor<16>([&](auto K) {
        constexpr int k = decltype(K)::v;
        float a0 = 0.f, a1 = 0.f, a2 = 0.f, a3 = 0.f;
        sfor<8>([&](auto J) {
            constexpr int j = decltype(J)::v;
            float4 va = lds_a4(As, lr, j);
            float4 vb = lds_a4(As, k, j);
            a0 += va.x*vb.x; a1 += va.y*vb.y; a2 += va.z*vb.z; a3 += va.w*vb.w;
        });
        Mrow[k] = (a0+a1)+(a2+a3) + ((k == lr) ? kJitter : 0.f);
        Vrow[k] = (k == lr) ? 1.f : 0.f;
    });

    // ---- Gauss-Jordan inverse (SPD -> no pivoting), width-32 shuffles
    sfor<16>([&](auto K) {
        constexpr int k = decltype(K)::v;
        float ip = 1.f / __shfl(Mrow[k], k, 32);
        float f  = (lr == k) ? 0.f : Mrow[k] * ip;
        sfor<16>([&](auto J) {
            constexpr int j = decltype(J)::v;
            float mj = __shfl(Mrow[j], k, 32);
            Mrow[j] = (lr == k) ? mj * ip : Mrow[j] - f * mj;
            float vj = __shfl(Vrow[j], k, 32);
            Vrow[j] = (lr == k) ? vj * ip : Vrow[j] - f * vj;
        });
    });

    // ---- w = Minv b while Vrow is live (lane holds w[lr], dup in upper half)
    float w = 0.f;
    {
        float bval = bg[gs * MD + lr];
        sfor<16>([&](auto K) {
            constexpr int k = decltype(K)::v;
            w += Vrow[k] * __shfl(bval, k, 32);
        });
    }

    // ---- hand Minv to LDS (row lr); Vrow dead after. Same-wave producers/consumers.
    if (l < 16) {
        sfor<4>([&](auto J) {
            constexpr int j = decltype(J)::v;
            *reinterpret_cast<float4*>(&Mi[lr * MIS + 4*j]) =
                make_float4(Vrow[4*j+0], Vrow[4*j+1], Vrow[4*j+2], Vrow[4*j+3]);
        });
    }
    asm volatile("s_waitcnt lgkmcnt(0)" ::: "memory");

    // ---- C row l of A^T Minv: C[m] = sum_k A[k][l] * Minv[k][m] (Minv uniform b128)
    f16v C = (f16v)0.0f;
    sfor<16>([&](auto K) {
        constexpr int k = decltype(K)::v;
        float a = lds_a(As, k, l);
        sfor<4>([&](auto J) {
            constexpr int j = decltype(J)::v;
            float4 mv = *reinterpret_cast<const float4*>(&Mi[k * MIS + 4*j]);
            C[4*j+0] += a * mv.x; C[4*j+1] += a * mv.y;
            C[4*j+2] += a * mv.z; C[4*j+3] += a * mv.w;
        });
    });

    // ---- P row l = (I - C A)/sigma: Pa[n]=P[l][n], Pb[n]=P[l][n+16]
    f16v Pa = (f16v)0.0f, Pb = (f16v)0.0f;
    sfor<16>([&](auto M) {
        constexpr int m = decltype(M)::v;
        float cm = C[m];
        sfor<4>([&](auto J) {
            constexpr int j = decltype(J)::v;
            float4 v  = lds_a4(As, m, j);
            Pa[4*j+0] += cm*v.x;  Pa[4*j+1] += cm*v.y;
            Pa[4*j+2] += cm*v.z;  Pa[4*j+3] += cm*v.w;
            float4 w4 = lds_a4(As, m, j + 4);
            Pb[4*j+0] += cm*w4.x; Pb[4*j+1] += cm*w4.y;
            Pb[4*j+2] += cm*w4.z; Pb[4*j+3] += cm*w4.w;
        });
    });
    constexpr float is = 1.f / kSigma;
    sfor<16>([&](auto N) {
        constexpr int n = decltype(N)::v;
        Pa[n] = (((n      == l) ? 1.f : 0.f) - Pa[n]) * is;
        Pb[n] = (((n + 16 == l) ? 1.f : 0.f) - Pb[n]) * is;
    });

    // ---- d = A^T w - P c
    float d;
    {
        float q = 0.f;
        sfor<16>([&](auto M) {
            constexpr int m = decltype(M)::v;
            q += lds_a(As, m, l) * __shfl(w, m, 32);
        });
        float cval = cg[gs * ND + l];
        float pc0 = 0.f, pc1 = 0.f;
        sfor<16>([&](auto N) {
            constexpr int n = decltype(N)::v;
            pc0 += Pa[n] * __shfl(cval, n,      32);
            pc1 += Pb[n] * __shfl(cval, n + 16, 32);
        });
        d = q - (pc0 + pc1);
    }

    // ---- store P row l (8 f4 = 128B contiguous per lane) and d
    float4* Pout = reinterpret_cast<float4*>(Pws + gs * (ND * ND)) + l * 8;
    sfor<4>([&](auto J) {
        constexpr int j = decltype(J)::v;
        Pout[j]     = make_float4(Pa[4*j+0], Pa[4*j+1], Pa[4*j+2], Pa[4*j+3]);
        Pout[j + 4] = make_float4(Pb[4*j+0], Pb[4*j+1], Pb[4*j+2], Pb[4*j+3]);
    });
    dws[gs * ND + l] = d;
}

// ============================ Kernel B: 100 ADMM iterations ============================
// Only named scalars / float4s -> guaranteed SSA, no alloca, low VGPR.
__global__ void __launch_bounds__(256)
admm_iter_kernel(const float* __restrict__ Pws, const float* __restrict__ dws,
                 const float* __restrict__ lbg, const float* __restrict__ ubg,
                 float* __restrict__ outg)
{
    __shared__ __align__(16) float S_lds[SPB * SS];   // 1152 B

    const int t = threadIdx.x;
    const int lane = t & 63;
    const int l = lane & 31;
    const int smp = (t >> 6) * 2 + (lane >> 5);
    const size_t gs = (size_t)blockIdx.x * SPB + smp;
    float* Sb = &S_lds[smp * SS];

    const float4* Prow = reinterpret_cast<const float4*>(Pws + gs * (ND * ND)) + l * 8;
    float4 p0 = Prow[0], p1 = Prow[1], p2 = Prow[2], p3 = Prow[3];
    float4 p4 = Prow[4], p5 = Prow[5], p6 = Prow[6], p7 = Prow[7];
    float dv = dws[gs * ND + l];
    float lb = lbg[gs * ND + l];
    float ub = ubg[gs * ND + l];
    float z  = fminf(fmaxf(0.f, lb), ub);
    float u  = 0.f, x = 0.f;

    const float4* Sv = reinterpret_cast<const float4*>(Sb);
    for (int it = 0; it < kIters; ++it) {
        Sb[l] = z - u;                                     // rho == 1
        asm volatile("s_waitcnt lgkmcnt(0)" ::: "memory"); // wave-synchronous exchange
        float4 s0 = Sv[0], s1 = Sv[1], s2 = Sv[2], s3 = Sv[3];   // uniform b128 broadcast
        float4 s4 = Sv[4], s5 = Sv[5], s6 = Sv[6], s7 = Sv[7];
        float a0 = fmaf(p0.w,s0.w, fmaf(p0.z,s0.z, fmaf(p0.y,s0.y, fmaf(p0.x,s0.x, dv))));
        float a1 = fmaf(p1.w,s1.w, fmaf(p1.z,s1.z, fmaf(p1.y,s1.y, p1.x*s1.x)));
        float a2 = fmaf(p2.w,s2.w, fmaf(p2.z,s2.z, fmaf(p2.y,s2.y, p2.x*s2.x)));
        float a3 = fmaf(p3.w,s3.w, fmaf(p3.z,s3.z, fmaf(p3.y,s3.y, p3.x*s3.x)));
        float a4 = fmaf(p4.w,s4.w, fmaf(p4.z,s4.z, fmaf(p4.y,s4.y, p4.x*s4.x)));
        float a5 = fmaf(p5.w,s5.w, fmaf(p5.z,s5.z, fmaf(p5.y,s5.y, p5.x*s5.x)));
        float a6 = fmaf(p6.w,s6.w, fmaf(p6.z,s6.z, fmaf(p6.y,s6.y, p6.x*s6.x)));
        float a7 = fmaf(p7.w,s7.w, fmaf(p7.z,s7.z, fmaf(p7.y,s7.y, p7.x*s7.x)));
        x = ((a0 + a1) + (a2 + a3)) + ((a4 + a5) + (a6 + a7));
        float tv = x + u;
        z = fminf(fmaxf(tv, lb), ub);
        u = tv - z;
    }

    outg[gs * ND + l] = x;
}

// ==================== Fallback: R6 single kernel (if ws too small) ====================
__global__ void __launch_bounds__(256)
admm_qp_kernel(const float* __restrict__ Ag, const float* __restrict__ bg,
               const float* __restrict__ cg, const float* __restrict__ lbg,
               const float* __restrict__ ubg, float* __restrict__ outg)
{
    __shared__ __align__(16) float A_lds[SPB * AS * 4];
    __shared__ __align__(16) float S_lds[SPB * SS];

    const int t = threadIdx.x;
    {
        const float4* src = reinterpret_cast<const float4*>(Ag) +
                            (size_t)blockIdx.x * (SPB * MD * ND / 4);
        float4* dst = reinterpret_cast<float4*>(A_lds);
        #pragma unroll
        for (int r = 0; r < 4; ++r) {
            int idx = r * 256 + t;
            int smp = idx >> 7;
            int row = (idx >> 3) & 15;
            int j   = idx & 7;
            dst[smp * AS + row * 8 + (j ^ (row & 7))] = src[idx];
        }
    }
    __syncthreads();

    const int lane = t & 63;
    const int l    = lane & 31;
    const int lr   = l & 15;
    const int smp  = (t >> 6) * 2 + (lane >> 5);
    const size_t gs = (size_t)blockIdx.x * SPB + smp;
    const float* As = &A_lds[smp * AS * 4];
    float* Sb = &S_lds[smp * SS];

    f16v Mrow, Vrow;
    sfor<16>([&](auto K) {
        constexpr int k = decltype(K)::v;
        float a0 = 0.f, a1 = 0.f, a2 = 0.f, a3 = 0.f;
        sfor<8>([&](auto J) {
            constexpr int j = decltype(J)::v;
            float4 va = lds_a4(As, lr, j);
            float4 vb = lds_a4(As, k, j);
            a0 += va.x*vb.x; a1 += va.y*vb.y; a2 += va.z*vb.z; a3 += va.w*vb.w;
        });
        Mrow[k] = (a0+a1)+(a2+a3) + ((k == lr) ? kJitter : 0.f);
        Vrow[k] = (k == lr) ? 1.f : 0.f;
    });
    sfor<16>([&](auto K) {
        constexpr int k = decltype(K)::v;
        float ip = 1.f / __shfl(Mrow[k], k, 32);
        float f  = (lr == k) ? 0.f : Mrow[k] * ip;
        sfor<16>([&](auto J) {
            constexpr int j = decltype(J)::v;
            float mj = __shfl(Mrow[j], k, 32);
            Mrow[j] = (lr == k) ? mj * ip : Mrow[j] - f * mj;
            float vj = __shfl(Vrow[j], k, 32);
            Vrow[j] = (lr == k) ? vj * ip : Vrow[j] - f * vj;
        });
    });
    float w = 0.f;
    {
        float bval = bg[gs * MD + lr];
        sfor<16>([&](auto K) {
            constexpr int k = decltype(K)::v;
            w += Vrow[k] * __shfl(bval, k, 32);
        });
    }
    f16v C = (f16v)0.0f;
    sfor<16>([&](auto K) {
        constexpr int k = decltype(K)::v;
        float a = lds_a(As, k, l);
        sfor<16>([&](auto M) {
            constexpr int m = decltype(M)::v;
            C[m] += a * __shfl(Vrow[m], k, 32);
        });
    });
    f16v Pa = (f16v)0.0f, Pb = (f16v)0.0f;
    sfor<16>([&](auto M) {
        constexpr int m = decltype(M)::v;
        float cm = C[m];
        sfor<4>([&](auto J) {
            constexpr int j = decltype(J)::v;
            float4 v  = lds_a4(As, m, j);
            Pa[4*j+0] += cm*v.x;  Pa[4*j+1] += cm*v.y;
            Pa[4*j+2] += cm*v.z;  Pa[4*j+3] += cm*v.w;
            float4 w4 = lds_a4(As, m, j + 4);
            Pb[4*j+0] += cm*w4.x; Pb[4*j+1] += cm*w4.y;
            Pb[4*j+2] += cm*w4.z; Pb[4*j+3] += cm*w4.w;
        });
    });
    constexpr float is = 1.f / kSigma;
    sfor<16>([&](auto N) {
        constexpr int n = decltype(N)::v;
        Pa[n] = (((n      == l) ? 1.f : 0.f) - Pa[n]) * is;
        Pb[n] = (((n + 16 == l) ? 1.f : 0.f) - Pb[n]) * is;
    });
    float d;
    {
        float q = 0.f;
        sfor<16>([&](auto M) {
            constexpr int m = decltype(M)::v;
            q += lds_a(As, m, l) * __shfl(w, m, 32);
        });
        float cval = cg[gs * ND + l];
        float pc0 = 0.f, pc1 = 0.f;
        sfor<16>([&](auto N) {
            constexpr int n = decltype(N)::v;
            pc0 += Pa[n] * __shfl(cval, n,      32);
            pc1 += Pb[n] * __shfl(cval, n + 16, 32);
        });
        d = q - (pc0 + pc1);
    }
    float lb = lbg[gs * ND + l];
    float ub = ubg[gs * ND + l];
    float z  = fminf(fmaxf(0.f, lb), ub);
    float u  = 0.f, x = 0.f;
    for (int it = 0; it < kIters; ++it) {
        Sb[l] = z - u;
        asm volatile("s_waitcnt lgkmcnt(0)" ::: "memory");
        float a0 = d, a1 = 0.f, a2 = 0.f, a3 = 0.f;
        sfor<4>([&](auto K) {
            constexpr int k = decltype(K)::v;
            float4 sA = *reinterpret_cast<const float4*>(&Sb[4*k]);
            float4 sB = *reinterpret_cast<const float4*>(&Sb[4*k + 16]);
            a0 += Pa[4*k+0]*sA.x + Pb[4*k+0]*sB.x;
            a1 += Pa[4*k+1]*sA.y + Pb[4*k+1]*sB.y;
            a2 += Pa[4*k+2]*sA.z + Pb[4*k+2]*sB.z;
            a3 += Pa[4*k+3]*sA.w + Pb[4*k+3]*sB.w;
        });
        x = (a0 + a1) + (a2 + a3);
        float tv = x + u;
        z = fminf(fmaxf(tv, lb), ub);
        u = tv - z;
    }
    outg[gs * ND + l] = x;
}

extern "C" void kernel_launch(void* const* d_in, const int* in_sizes, int n_in,
                              void* d_out, int out_size, void* d_ws, size_t ws_size,
                              hipStream_t stream) {
    const float* A  = (const float*)d_in[0];
    const float* b  = (const float*)d_in[1];
    const float* c  = (const float*)d_in[2];
    const float* lb = (const float*)d_in[3];
    const float* ub = (const float*)d_in[4];
    float* out = (float*)d_out;
    const int B = in_sizes[1] / MD;                       // 32768 samples
    const int grid = B / SPB;                             // 4096 blocks
    const size_t needP = (size_t)B * ND * ND * sizeof(float);   // 128 MiB
    const size_t needD = (size_t)B * ND * sizeof(float);        // 4 MiB
    if (ws_size >= needP + needD) {
        float* Pws = (float*)d_ws;
        float* dws = Pws + (size_t)B * ND * ND;
        precompute_kernel<<<grid, 256, 0, stream>>>(A, b, c, Pws, dws);
        admm_iter_kernel<<<grid, 256, 0, stream>>>(Pws, dws, lb, ub, out);
    } else {
        admm_qp_kernel<<<grid, 256, 0, stream>>>(A, b, c, lb, ub, out);
    }
}

// Round 8
// 232.133 us; speedup vs baseline: 5.5688x; 1.4838x over previous
//
#include <hip/hip_runtime.h>

typedef float f16v __attribute__((ext_vector_type(16)));
typedef float f4 __attribute__((ext_vector_type(4)));
typedef float f2 __attribute__((ext_vector_type(2)));

// static_for with FRONTEND-constant indices: vector subscripts lower to
// constant-index insert/extractelement (SSA, no alloca). #pragma unroll loop
// vars are not frontend-constant -> variable GEP -> alloca -> scratch traffic
// (R1-R5's GBs of FETCH/WRITE; R6/R7 fixed it with this).
template<int I> struct ic { static constexpr int v = I; };
template<int... I> struct iseq {};
template<int N, int... I> struct mk : mk<N-1, N-1, I...> {};
template<int... I> struct mk<0, I...> { using t = iseq<I...>; };
template<class F, int... I>
__device__ __forceinline__ void sfor_impl(F f, iseq<I...>) { (f(ic<I>{}), ...); }
template<int N, class F>
__device__ __forceinline__ void sfor(F f) { sfor_impl(f, typename mk<N>::t{}); }

namespace {
constexpr float kSigma  = 1.2f;    // 2*l2_reg + rho
constexpr float kJitter = 1e-5f;
constexpr int   kIters  = 100;
constexpr int   MD = 16;     // constraint rows
constexpr int   ND = 32;     // variables
constexpr int   SPB = 8;     // samples per block in precompute (32 lanes each)
constexpr int   SPB2 = 16;   // samples per block in iter kernel (16 lanes each)
constexpr int   AS  = 132;   // A sample stride in float4 (528 floats; 528%32==16)
constexpr int   SS  = 36;    // s-slot stride in floats
constexpr int   MIS = 20;    // Minv row stride in floats (80B: b128-aligned, 2-way banks)
}

// A tile in LDS: per sample 16 rows x 8 float4, f4 index xor-swizzled with row.
__device__ __forceinline__ float4 lds_a4(const float* As, int r, int j) {
    return *reinterpret_cast<const float4*>(&As[r * 32 + ((j ^ (r & 7)) << 2)]);
}
__device__ __forceinline__ float lds_a(const float* As, int r, int n) {
    return As[r * 32 + ((((n >> 2) ^ (r & 7)) << 2) | (n & 3))];
}

// ============================ Kernel A: precompute P, d ============================
// P stored interleaved: Pws[sample][N][row] as f2, N=0..15 covers cols (2N,2N+1).
// A-lane l (row l) writes f2 (P[l][2N],P[l][2N+1]) at float offset gs*1024 + N*64 + l*2
// -> consecutive lanes write consecutive 8B (coalesced). Kernel B lane bl reads one f4
// at N*64 + bl*4 = rows (2bl,2bl+1) cols (2N,2N+1), perfectly coalesced.
__global__ void __launch_bounds__(256)
precompute_kernel(const float* __restrict__ Ag, const float* __restrict__ bg,
                  const float* __restrict__ cg, float* __restrict__ Pws,
                  float* __restrict__ dws)
{
    __shared__ __align__(16) float A_lds[SPB * AS * 4];       // 16896 B
    __shared__ __align__(16) float Minv_lds[SPB * MD * MIS];  // 10240 B

    const int t = threadIdx.x;

    // ---- stage A for the block's 8 samples (coalesced, xor-swizzled f4)
    {
        const float4* src = reinterpret_cast<const float4*>(Ag) +
                            (size_t)blockIdx.x * (SPB * MD * ND / 4);
        float4* dst = reinterpret_cast<float4*>(A_lds);
        #pragma unroll
        for (int r = 0; r < 4; ++r) {
            int idx = r * 256 + t;
            int smp = idx >> 7;
            int row = (idx >> 3) & 15;
            int j   = idx & 7;
            dst[smp * AS + row * 8 + (j ^ (row & 7))] = src[idx];
        }
    }
    __syncthreads();

    const int lane = t & 63;
    const int l    = lane & 31;
    const int lr   = l & 15;
    const int smp  = (t >> 6) * 2 + (lane >> 5);
    const size_t gs = (size_t)blockIdx.x * SPB + smp;
    const float* As = &A_lds[smp * AS * 4];
    float* Mi = &Minv_lds[smp * MD * MIS];

    // ---- M = A A^T + jitter*I (row lr); both operand rows from LDS (no Ar regs)
    f16v Mrow, Vrow;
    sfor<16>([&](auto K) {
        constexpr int k = decltype(K)::v;
        float a0 = 0.f, a1 = 0.f, a2 = 0.f, a3 = 0.f;
        sfor<8>([&](auto J) {
            constexpr int j = decltype(J)::v;
            float4 va = lds_a4(As, lr, j);
            float4 vb = lds_a4(As, k, j);
            a0 += va.x*vb.x; a1 += va.y*vb.y; a2 += va.z*vb.z; a3 += va.w*vb.w;
        });
        Mrow[k] = (a0+a1)+(a2+a3) + ((k == lr) ? kJitter : 0.f);
        Vrow[k] = (k == lr) ? 1.f : 0.f;
    });

    // ---- Gauss-Jordan inverse (SPD -> no pivoting), width-32 shuffles
    sfor<16>([&](auto K) {
        constexpr int k = decltype(K)::v;
        float ip = 1.f / __shfl(Mrow[k], k, 32);
        float f  = (lr == k) ? 0.f : Mrow[k] * ip;
        sfor<16>([&](auto J) {
            constexpr int j = decltype(J)::v;
            float mj = __shfl(Mrow[j], k, 32);
            Mrow[j] = (lr == k) ? mj * ip : Mrow[j] - f * mj;
            float vj = __shfl(Vrow[j], k, 32);
            Vrow[j] = (lr == k) ? vj * ip : Vrow[j] - f * vj;
        });
    });

    // ---- w = Minv b while Vrow is live (lane holds w[lr], dup in upper half)
    float w = 0.f;
    {
        float bval = bg[gs * MD + lr];
        sfor<16>([&](auto K) {
            constexpr int k = decltype(K)::v;
            w += Vrow[k] * __shfl(bval, k, 32);
        });
    }

    // ---- hand Minv to LDS (row lr); Vrow dead after. Same-wave producers/consumers.
    if (l < 16) {
        sfor<4>([&](auto J) {
            constexpr int j = decltype(J)::v;
            *reinterpret_cast<float4*>(&Mi[lr * MIS + 4*j]) =
                make_float4(Vrow[4*j+0], Vrow[4*j+1], Vrow[4*j+2], Vrow[4*j+3]);
        });
    }
    asm volatile("s_waitcnt lgkmcnt(0)" ::: "memory");

    // ---- C row l of A^T Minv: C[m] = sum_k A[k][l] * Minv[k][m] (Minv uniform b128)
    f16v C = (f16v)0.0f;
    sfor<16>([&](auto K) {
        constexpr int k = decltype(K)::v;
        float a = lds_a(As, k, l);
        sfor<4>([&](auto J) {
            constexpr int j = decltype(J)::v;
            float4 mv = *reinterpret_cast<const float4*>(&Mi[k * MIS + 4*j]);
            C[4*j+0] += a * mv.x; C[4*j+1] += a * mv.y;
            C[4*j+2] += a * mv.z; C[4*j+3] += a * mv.w;
        });
    });

    // ---- P row l = (I - C A)/sigma: Pa[n]=P[l][n], Pb[n]=P[l][n+16]
    f16v Pa = (f16v)0.0f, Pb = (f16v)0.0f;
    sfor<16>([&](auto M) {
        constexpr int m = decltype(M)::v;
        float cm = C[m];
        sfor<4>([&](auto J) {
            constexpr int j = decltype(J)::v;
            float4 v  = lds_a4(As, m, j);
            Pa[4*j+0] += cm*v.x;  Pa[4*j+1] += cm*v.y;
            Pa[4*j+2] += cm*v.z;  Pa[4*j+3] += cm*v.w;
            float4 w4 = lds_a4(As, m, j + 4);
            Pb[4*j+0] += cm*w4.x; Pb[4*j+1] += cm*w4.y;
            Pb[4*j+2] += cm*w4.z; Pb[4*j+3] += cm*w4.w;
        });
    });
    constexpr float is = 1.f / kSigma;
    sfor<16>([&](auto N) {
        constexpr int n = decltype(N)::v;
        Pa[n] = (((n      == l) ? 1.f : 0.f) - Pa[n]) * is;
        Pb[n] = (((n + 16 == l) ? 1.f : 0.f) - Pb[n]) * is;
    });

    // ---- d = A^T w - P c
    float d;
    {
        float q = 0.f;
        sfor<16>([&](auto M) {
            constexpr int m = decltype(M)::v;
            q += lds_a(As, m, l) * __shfl(w, m, 32);
        });
        float cval = cg[gs * ND + l];
        float pc0 = 0.f, pc1 = 0.f;
        sfor<16>([&](auto N) {
            constexpr int n = decltype(N)::v;
            pc0 += Pa[n] * __shfl(cval, n,      32);
            pc1 += Pb[n] * __shfl(cval, n + 16, 32);
        });
        d = q - (pc0 + pc1);
    }

    // ---- store P row l as 16 interleaved f2 (coalesced), and d
    {
        f2* Pout = reinterpret_cast<f2*>(Pws + gs * (ND * ND));
        sfor<8>([&](auto N) {
            constexpr int n = decltype(N)::v;
            f2 e; e[0] = Pa[2*n]; e[1] = Pa[2*n+1];
            Pout[n * 32 + l] = e;                       // cols 2n,2n+1
            f2 o; o[0] = Pb[2*n]; o[1] = Pb[2*n+1];
            Pout[(n + 8) * 32 + l] = o;                 // cols 16+2n,16+2n+1
        });
    }
    dws[gs * ND + l] = d;
}

// ============================ Kernel B: 100 ADMM iterations ============================
// 16 lanes/sample, 2 adjacent variables per lane (rows 2l, 2l+1 of P).
// All state named f2/f4 ext-vectors -> SSA; elementwise_fma -> v_pk_fma_f32.
__global__ void __launch_bounds__(256)
admm_iter_kernel(const float* __restrict__ Pws, const float* __restrict__ dws,
                 const float* __restrict__ lbg, const float* __restrict__ ubg,
                 float* __restrict__ outg)
{
    __shared__ __align__(16) float S_lds[SPB2 * SS];   // 2304 B

    const int t = threadIdx.x;
    const int lane = t & 63;
    const int l = lane & 15;                       // lane within 16-lane group
    const int smp = (t >> 6) * 4 + (lane >> 4);    // sample within block
    const size_t gs = (size_t)blockIdx.x * SPB2 + smp;
    float* Sb = &S_lds[smp * SS];

    // p_N = (P[2l][2N], P[2l][2N+1], P[2l+1][2N], P[2l+1][2N+1]); coalesced f4 loads
    const f4* Pw = reinterpret_cast<const f4*>(Pws + gs * (ND * ND));
    f4 p0  = Pw[ 0*16 + l], p1  = Pw[ 1*16 + l], p2  = Pw[ 2*16 + l], p3  = Pw[ 3*16 + l];
    f4 p4  = Pw[ 4*16 + l], p5  = Pw[ 5*16 + l], p6  = Pw[ 6*16 + l], p7  = Pw[ 7*16 + l];
    f4 p8  = Pw[ 8*16 + l], p9  = Pw[ 9*16 + l], p10 = Pw[10*16 + l], p11 = Pw[11*16 + l];
    f4 p12 = Pw[12*16 + l], p13 = Pw[13*16 + l], p14 = Pw[14*16 + l], p15 = Pw[15*16 + l];

    f2 dv = *reinterpret_cast<const f2*>(dws + gs * ND + 2 * l);
    f2 lb = *reinterpret_cast<const f2*>(lbg + gs * ND + 2 * l);
    f2 ub = *reinterpret_cast<const f2*>(ubg + gs * ND + 2 * l);
    f2 z  = __builtin_elementwise_min(__builtin_elementwise_max((f2)0.0f, lb), ub);
    f2 u  = (f2)0.0f;
    f2 x  = (f2)0.0f;

    const f4* Sv = reinterpret_cast<const f4*>(Sb);
    for (int it = 0; it < kIters; ++it) {
        *reinterpret_cast<f2*>(&Sb[2 * l]) = z - u;        // rho == 1
        asm volatile("s_waitcnt lgkmcnt(0)" ::: "memory"); // wave-synchronous exchange
        // acc.x: row 2l / .y: row 2l (odd cols) / .z,.w: row 2l+1
        f4 acc0; acc0[0] = dv[0]; acc0[1] = 0.f; acc0[2] = dv[1]; acc0[3] = 0.f;
        f4 acc1 = (f4)0.0f;
#define QP_STEP(q, PA, PB)                                                   \
        {                                                                    \
            f4 S4 = Sv[q];           /* uniform: (s[4q..4q+3]) broadcast */  \
            f4 m0 = __builtin_shufflevector(S4, S4, 0, 1, 0, 1);             \
            f4 m1 = __builtin_shufflevector(S4, S4, 2, 3, 2, 3);             \
            acc0 = __builtin_elementwise_fma(PA, m0, acc0);                  \
            acc1 = __builtin_elementwise_fma(PB, m1, acc1);                  \
        }
        QP_STEP(0, p0,  p1)  QP_STEP(1, p2,  p3)
        QP_STEP(2, p4,  p5)  QP_STEP(3, p6,  p7)
        QP_STEP(4, p8,  p9)  QP_STEP(5, p10, p11)
        QP_STEP(6, p12, p13) QP_STEP(7, p14, p15)
#undef QP_STEP
        f4 s4 = acc0 + acc1;
        x = __builtin_shufflevector(s4, s4, 0, 2) + __builtin_shufflevector(s4, s4, 1, 3);
        f2 tv = x + u;
        z = __builtin_elementwise_min(__builtin_elementwise_max(tv, lb), ub);
        u = tv - z;
    }

    *reinterpret_cast<f2*>(outg + gs * ND + 2 * l) = x;
}

// ==================== Fallback: R6 single kernel (if ws too small) ====================
__global__ void __launch_bounds__(256)
admm_qp_kernel(const float* __restrict__ Ag, const float* __restrict__ bg,
               const float* __restrict__ cg, const float* __restrict__ lbg,
               const float* __restrict__ ubg, float* __restrict__ outg)
{
    __shared__ __align__(16) float A_lds[SPB * AS * 4];
    __shared__ __align__(16) float S_lds[SPB * SS];

    const int t = threadIdx.x;
    {
        const float4* src = reinterpret_cast<const float4*>(Ag) +
                            (size_t)blockIdx.x * (SPB * MD * ND / 4);
        float4* dst = reinterpret_cast<float4*>(A_lds);
        #pragma unroll
        for (int r = 0; r < 4; ++r) {
            int idx = r * 256 + t;
            int smp = idx >> 7;
            int row = (idx >> 3) & 15;
            int j   = idx & 7;
            dst[smp * AS + row * 8 + (j ^ (row & 7))] = src[idx];
        }
    }
    __syncthreads();

    const int lane = t & 63;
    const int l    = lane & 31;
    const int lr   = l & 15;
    const int smp  = (t >> 6) * 2 + (lane >> 5);
    const size_t gs = (size_t)blockIdx.x * SPB + smp;
    const float* As = &A_lds[smp * AS * 4];
    float* Sb = &S_lds[smp * SS];

    f16v Mrow, Vrow;
    sfor<16>([&](auto K) {
        constexpr int k = decltype(K)::v;
        float a0 = 0.f, a1 = 0.f, a2 = 0.f, a3 = 0.f;
        sfor<8>([&](auto J) {
            constexpr int j = decltype(J)::v;
            float4 va = lds_a4(As, lr, j);
            float4 vb = lds_a4(As, k, j);
            a0 += va.x*vb.x; a1 += va.y*vb.y; a2 += va.z*vb.z; a3 += va.w*vb.w;
        });
        Mrow[k] = (a0+a1)+(a2+a3) + ((k == lr) ? kJitter : 0.f);
        Vrow[k] = (k == lr) ? 1.f : 0.f;
    });
    sfor<16>([&](auto K) {
        constexpr int k = decltype(K)::v;
        float ip = 1.f / __shfl(Mrow[k], k, 32);
        float f  = (lr == k) ? 0.f : Mrow[k] * ip;
        sfor<16>([&](auto J) {
            constexpr int j = decltype(J)::v;
            float mj = __shfl(Mrow[j], k, 32);
            Mrow[j] = (lr == k) ? mj * ip : Mrow[j] - f * mj;
            float vj = __shfl(Vrow[j], k, 32);
            Vrow[j] = (lr == k) ? vj * ip : Vrow[j] - f * vj;
        });
    });
    float w = 0.f;
    {
        float bval = bg[gs * MD + lr];
        sfor<16>([&](auto K) {
            constexpr int k = decltype(K)::v;
            w += Vrow[k] * __shfl(bval, k, 32);
        });
    }
    f16v C = (f16v)0.0f;
    sfor<16>([&](auto K) {
        constexpr int k = decltype(K)::v;
        float a = lds_a(As, k, l);
        sfor<16>([&](auto M) {
            constexpr int m = decltype(M)::v;
            C[m] += a * __shfl(Vrow[m], k, 32);
        });
    });
    f16v Pa = (f16v)0.0f, Pb = (f16v)0.0f;
    sfor<16>([&](auto M) {
        constexpr int m = decltype(M)::v;
        float cm = C[m];
        sfor<4>([&](auto J) {
            constexpr int j = decltype(J)::v;
            float4 v  = lds_a4(As, m, j);
            Pa[4*j+0] += cm*v.x;  Pa[4*j+1] += cm*v.y;
            Pa[4*j+2] += cm*v.z;  Pa[4*j+3] += cm*v.w;
            float4 w4 = lds_a4(As, m, j + 4);
            Pb[4*j+0] += cm*w4.x; Pb[4*j+1] += cm*w4.y;
            Pb[4*j+2] += cm*w4.z; Pb[4*j+3] += cm*w4.w;
        });
    });
    constexpr float is = 1.f / kSigma;
    sfor<16>([&](auto N) {
        constexpr int n = decltype(N)::v;
        Pa[n] = (((n      == l) ? 1.f : 0.f) - Pa[n]) * is;
        Pb[n] = (((n + 16 == l) ? 1.f : 0.f) - Pb[n]) * is;
    });
    float d;
    {
        float q = 0.f;
        sfor<16>([&](auto M) {
            constexpr int m = decltype(M)::v;
            q += lds_a(As, m, l) * __shfl(w, m, 32);
        });
        float cval = cg[gs * ND + l];
        float pc0 = 0.f, pc1 = 0.f;
        sfor<16>([&](auto N) {
            constexpr int n = decltype(N)::v;
            pc0 += Pa[n] * __shfl(cval, n,      32);
            pc1 += Pb[n] * __shfl(cval, n + 16, 32);
        });
        d = q - (pc0 + pc1);
    }
    float lb = lbg[gs * ND + l];
    float ub = ubg[gs * ND + l];
    float z  = fminf(fmaxf(0.f, lb), ub);
    float u  = 0.f, x = 0.f;
    for (int it = 0; it < kIters; ++it) {
        Sb[l] = z - u;
        asm volatile("s_waitcnt lgkmcnt(0)" ::: "memory");
        float a0 = d, a1 = 0.f, a2 = 0.f, a3 = 0.f;
        sfor<4>([&](auto K) {
            constexpr int k = decltype(K)::v;
            float4 sA = *reinterpret_cast<const float4*>(&Sb[4*k]);
            float4 sB = *reinterpret_cast<const float4*>(&Sb[4*k + 16]);
            a0 += Pa[4*k+0]*sA.x + Pb[4*k+0]*sB.x;
            a1 += Pa[4*k+1]*sA.y + Pb[4*k+1]*sB.y;
            a2 += Pa[4*k+2]*sA.z + Pb[4*k+2]*sB.z;
            a3 += Pa[4*k+3]*sA.w + Pb[4*k+3]*sB.w;
        });
        x = (a0 + a1) + (a2 + a3);
        float tv = x + u;
        z = fminf(fmaxf(tv, lb), ub);
        u = tv - z;
    }
    outg[gs * ND + l] = x;
}

extern "C" void kernel_launch(void* const* d_in, const int* in_sizes, int n_in,
                              void* d_out, int out_size, void* d_ws, size_t ws_size,
                              hipStream_t stream) {
    const float* A  = (const float*)d_in[0];
    const float* b  = (const float*)d_in[1];
    const float* c  = (const float*)d_in[2];
    const float* lb = (const float*)d_in[3];
    const float* ub = (const float*)d_in[4];
    float* out = (float*)d_out;
    const int B = in_sizes[1] / MD;                       // 32768 samples
    const size_t needP = (size_t)B * ND * ND * sizeof(float);   // 128 MiB
    const size_t needD = (size_t)B * ND * sizeof(float);        // 4 MiB
    if (ws_size >= needP + needD) {
        float* Pws = (float*)d_ws;
        float* dws = Pws + (size_t)B * ND * ND;
        precompute_kernel<<<B / SPB, 256, 0, stream>>>(A, b, c, Pws, dws);
        admm_iter_kernel<<<B / SPB2, 256, 0, stream>>>(Pws, dws, lb, ub, out);
    } else {
        admm_qp_kernel<<<B / SPB, 256, 0, stream>>>(A, b, c, lb, ub, out);
    }
}